// Round 10
// baseline (371.209 us; speedup 1.0000x reference)
//
#include <hip/hip_runtime.h>
#include <math.h>

#define N_NODES 100000
#define IN_DIM  512
#define HID     5
#define HEADS   5
#define C1      25   // HEADS*HID
#define NC      3
#define NEG     0.2f
#define NPB     64   // nodes per block in k_layer1
#define BSH     7    // 128 dsts per bucket
#define NBUCK   ((N_NODES + 127) >> BSH)   // 782
#define NDIG    1024 // padded bucket count (radix digits)
#define NBH     256  // hist/write blocks
#define HTH     1024 // hist/write threads per block

typedef float f32x4 __attribute__((ext_vector_type(4)));

__device__ __forceinline__ float lrelu(float v) { return v >= 0.f ? v : NEG * v; }

// ---- K1a: partial h1 = x @ W1, split-K x CH across blocks, 1-wave blocks.
// CH=4: 6252 waves (~6/SIMD) for latency hiding; thread (n,c) covers
// K in [c*(512/CH), (c+1)*(512/CH)). Partials column-major
// part[(c*25+j)][n] -> coalesced writes/reads. nt loads bypass L1
// (x rows are 2048B pow2 stride -> single-set aliasing; zero reuse).
template<int CH>
__global__ void __launch_bounds__(64)
k_gemm1(const float* __restrict__ x, const float* __restrict__ W1,
        float* __restrict__ part) {
    constexpr int KC = IN_DIM / CH;       // floats per chunk
    int b = blockIdx.x;
    int c = b & (CH - 1);
    int n = (b / CH) * 64 + threadIdx.x;
    if (n >= N_NODES) return;
    const f32x4* xr = (const f32x4*)(x + (size_t)n * IN_DIM) + c * (KC / 4);
    const float* Wb = W1 + (size_t)c * KC * C1;
    float acc[C1];
#pragma unroll
    for (int j = 0; j < C1; ++j) acc[j] = 0.f;
    for (int L = 0; L < KC / 16; ++L) {   // one 64B line per batch
        f32x4 xv[4];
#pragma unroll
        for (int q = 0; q < 4; ++q) xv[q] = __builtin_nontemporal_load(xr + L * 4 + q);
#pragma unroll
        for (int q = 0; q < 4; ++q) {
            const float* wr = Wb + (size_t)(L * 4 + q) * 4 * C1;  // wave-uniform -> s_load
#pragma unroll
            for (int j = 0; j < C1; ++j)
                acc[j] += xv[q].x * wr[j] + xv[q].y * wr[C1 + j]
                        + xv[q].z * wr[2 * C1 + j] + xv[q].w * wr[3 * C1 + j];
        }
    }
#pragma unroll
    for (int j = 0; j < C1; ++j)
        part[(size_t)(c * C1 + j) * N_NODES + n] = acc[j];   // coalesced store
}

// ---- K1b: reduce partials + epilogue (attention scalars, packed h1p row) ----
template<int CH>
__global__ void __launch_bounds__(256)
k_gemm1b(const float* __restrict__ part, const float* __restrict__ as1,
         const float* __restrict__ ad1, float* __restrict__ h1p,
         float* __restrict__ adst) {
    int n = blockIdx.x * blockDim.x + threadIdx.x;
    if (n >= N_NODES) return;
    float acc[C1];
#pragma unroll
    for (int j = 0; j < C1; ++j) acc[j] = 0.f;
#pragma unroll
    for (int c = 0; c < CH; ++c)
#pragma unroll
        for (int j = 0; j < C1; ++j)
            acc[j] += __builtin_nontemporal_load(part + (size_t)(c * C1 + j) * N_NODES + n);
    float rowbuf[32];
#pragma unroll
    for (int j = 0; j < C1; ++j) rowbuf[5 + j] = acc[j];
    rowbuf[30] = 0.f; rowbuf[31] = 0.f;
#pragma unroll
    for (int h = 0; h < HEADS; ++h) {
        float s = 0.f, d = 0.f;
#pragma unroll
        for (int c = 0; c < HID; ++c) {
            s += acc[h * HID + c] * as1[h * HID + c];
            d += acc[h * HID + c] * ad1[h * HID + c];
        }
        rowbuf[h] = s;
        adst[n * HEADS + h] = d;
    }
    float4* h4 = (float4*)(h1p + (size_t)n * 32);
#pragma unroll
    for (int q = 0; q < 8; ++q)
        h4[q] = make_float4(rowbuf[4 * q], rowbuf[4 * q + 1], rowbuf[4 * q + 2], rowbuf[4 * q + 3]);
}

// ---- radix pass 1: per-block LDS histogram over 1024 coarse buckets ----
__global__ void __launch_bounds__(HTH)
k_hist1(const int* __restrict__ ei, int E, int TOT, int* __restrict__ hist) {
    __shared__ int lh[NDIG];
    int b = blockIdx.x, tid = threadIdx.x;
    for (int i = tid; i < NDIG; i += HTH) lh[i] = 0;
    __syncthreads();
    int chunk = (TOT + NBH - 1) / NBH;
    int e0 = b * chunk, e1 = min(e0 + chunk, TOT);
    for (int e = e0 + tid; e < e1; e += HTH) {
        int d = (e < E) ? ei[E + e] : e - E;
        atomicAdd(&lh[d >> BSH], 1);
    }
    __syncthreads();
    for (int i = tid; i < NDIG; i += HTH) hist[b * NDIG + i] = lh[i];
}

// ---- radix: per-digit scan over blocks (hist[b][d] -> exclusive prefix; bcnt[d]=total) ----
__global__ void __launch_bounds__(NBH)
k_colscan(int* __restrict__ hist, int* __restrict__ bcnt) {
    __shared__ int sh[NBH];
    int d = blockIdx.x, t = threadIdx.x;
    int v = hist[t * NDIG + d];
    sh[t] = v;
    __syncthreads();
    for (int ofs = 1; ofs < NBH; ofs <<= 1) {
        int u = (t >= ofs) ? sh[t - ofs] : 0;
        __syncthreads();
        sh[t] += u;
        __syncthreads();
    }
    hist[t * NDIG + d] = sh[t] - v;   // exclusive over blocks
    if (t == NBH - 1) bcnt[d] = sh[t];
}

// ---- radix: exclusive scan of 1024 bucket counts ----
__global__ void __launch_bounds__(NDIG)
k_boff(const int* __restrict__ bcnt, int* __restrict__ boff) {
    __shared__ int sh[NDIG];
    int t = threadIdx.x;
    int v = bcnt[t];
    sh[t] = v;
    __syncthreads();
    for (int ofs = 1; ofs < NDIG; ofs <<= 1) {
        int u = (t >= ofs) ? sh[t - ofs] : 0;
        __syncthreads();
        sh[t] += u;
        __syncthreads();
    }
    boff[t] = sh[t] - v;
}

// ---- radix pass 2: write packed edges to bucket regions (LDS cursors, no global atomics) ----
__global__ void __launch_bounds__(HTH)
k_write(const int* __restrict__ ei, int E, int TOT, const int* __restrict__ hist,
        const int* __restrict__ boff, int* __restrict__ pk) {
    __shared__ int lbase[NDIG];
    __shared__ int lcur[NDIG];
    int b = blockIdx.x, tid = threadIdx.x;
    for (int i = tid; i < NDIG; i += HTH) {
        lbase[i] = boff[i] + hist[b * NDIG + i];
        lcur[i] = 0;
    }
    __syncthreads();
    int chunk = (TOT + NBH - 1) / NBH;
    int e0 = b * chunk, e1 = min(e0 + chunk, TOT);
    for (int e = e0 + tid; e < e1; e += HTH) {
        int s, d;
        if (e < E) { s = ei[e]; d = ei[E + e]; } else { s = d = e - E; }
        int dg = d >> BSH;
        int r = atomicAdd(&lcur[dg], 1);
        pk[lbase[dg] + r] = s | ((d & 127) << 17);
    }
}

// ---- per-bucket regroup by dst; emits off/deg and final ssrc (no global atomics) ----
__global__ void __launch_bounds__(512)
k_bgroup(const int* __restrict__ boff, const int* __restrict__ bcnt,
         const int* __restrict__ pk, int* __restrict__ off, int* __restrict__ deg,
         int* __restrict__ ssrc) {
    __shared__ int cnt[128], pref[128], lcur[128];
    int b = blockIdx.x, tid = threadIdx.x;
    int n0 = b << BSH;
    if (tid < 128) cnt[tid] = 0;
    __syncthreads();
    int r0 = boff[b], r1 = r0 + bcnt[b];
    for (int i = r0 + tid; i < r1; i += 512)
        atomicAdd(&cnt[(pk[i] >> 17) & 127], 1);
    __syncthreads();
    if (tid < 128) pref[tid] = cnt[tid];
    __syncthreads();
    for (int ofs = 1; ofs < 128; ofs <<= 1) {
        int u = 0;
        if (tid < 128 && tid >= ofs) u = pref[tid - ofs];
        __syncthreads();
        if (tid < 128) pref[tid] += u;
        __syncthreads();
    }
    if (tid < 128) {
        int n = n0 + tid;
        if (n < N_NODES) {
            off[n] = r0 + pref[tid] - cnt[tid];
            deg[n] = cnt[tid];
        }
        lcur[tid] = 0;
    }
    __syncthreads();
    for (int i = r0 + tid; i < r1; i += 512) {
        int v = pk[i];
        int dl = (v >> 17) & 127;
        int r = atomicAdd(&lcur[dl], 1);
        ssrc[r0 + pref[dl] - cnt[dl] + r] = v & 0x1FFFF;
    }
}

// ---- Layer 1: per-(dst,head) online softmax + aggregate; fused bias+ELU+W2+attn2 ----
__global__ void __launch_bounds__(NPB * HEADS)
k_layer1(const int* __restrict__ off, const int* __restrict__ deg, const int* __restrict__ ssrc,
         const float* __restrict__ h1p, const float* __restrict__ adst,
         const float* __restrict__ b1, const float* __restrict__ W2,
         const float* __restrict__ as2, const float* __restrict__ ad2,
         float4* __restrict__ n2, float* __restrict__ a2d) {
    __shared__ float sh[NPB * C1];
    int tid = threadIdx.x;            // 0..319
    int ln = tid / HEADS, h = tid % HEADS;
    int n = blockIdx.x * NPB + ln;
    if (n < N_NODES) {
        int st = off[n], cnt = deg[n];
        float adn = adst[n * HEADS + h];
        float m = -1e30f, den = 0.f;
        float num[HID] = {0.f, 0.f, 0.f, 0.f, 0.f};
        for (int i = 0; i < cnt; ++i) {
            int s = ssrc[st + i];
            const float* row = h1p + (size_t)s * 32;
            float v = lrelu(row[h] + adn);
            if (v > m) {
                float sc = __expf(m - v);
                den *= sc;
#pragma unroll
                for (int c = 0; c < HID; ++c) num[c] *= sc;
                m = v;
            }
            float p = __expf(v - m);
            den += p;
            const float* hr = row + 5 + h * HID;
#pragma unroll
            for (int c = 0; c < HID; ++c) num[c] += p * hr[c];
        }
        float inv = 1.f / den;
#pragma unroll
        for (int c = 0; c < HID; ++c) {
            float v = num[c] * inv + b1[h * HID + c];
            sh[ln * C1 + h * HID + c] = v > 0.f ? v : expm1f(v);
        }
    }
    __syncthreads();
    if (tid < NPB) {
        int nn = blockIdx.x * NPB + tid;
        if (nn < N_NODES) {
            float gg[NC] = {0.f, 0.f, 0.f};
#pragma unroll
            for (int j = 0; j < C1; ++j) {
                float hv = sh[tid * C1 + j];
#pragma unroll
                for (int c = 0; c < NC; ++c) gg[c] += hv * W2[j * NC + c];
            }
            float ssv = 0.f, ddv = 0.f;
#pragma unroll
            for (int c = 0; c < NC; ++c) { ssv += gg[c] * as2[c]; ddv += gg[c] * ad2[c]; }
            n2[nn] = make_float4(ssv, gg[0], gg[1], gg[2]);  // [a2s | g0 g1 g2]
            a2d[nn] = ddv;
        }
    }
}

// ---- Layer 2: per-dst online softmax + aggregate + log_sigmoid ----
__global__ void k_layer2(const int* __restrict__ off, const int* __restrict__ deg,
                         const int* __restrict__ ssrc, const float4* __restrict__ n2,
                         const float* __restrict__ a2d, const float* __restrict__ b2,
                         float* __restrict__ out) {
    int n = blockIdx.x * blockDim.x + threadIdx.x;
    if (n >= N_NODES) return;
    int st = off[n], cnt = deg[n];
    float adn = a2d[n];
    float m = -1e30f, den = 0.f, num0 = 0.f, num1 = 0.f, num2 = 0.f;
    for (int i = 0; i < cnt; ++i) {
        int s = ssrc[st + i];
        float4 gv = n2[s];
        float v = lrelu(gv.x + adn);
        if (v > m) {
            float sc = __expf(m - v);
            den *= sc; num0 *= sc; num1 *= sc; num2 *= sc;
            m = v;
        }
        float p = __expf(v - m);
        den += p;
        num0 += p * gv.y; num1 += p * gv.z; num2 += p * gv.w;
    }
    float inv = 1.f / den;
    float vv[NC] = {num0 * inv + b2[0], num1 * inv + b2[1], num2 * inv + b2[2]};
#pragma unroll
    for (int c = 0; c < NC; ++c) {
        float v = vv[c];
        out[n * NC + c] = (v >= 0.f) ? -log1pf(__expf(-v)) : v - log1pf(__expf(v));
    }
}

extern "C" void kernel_launch(void* const* d_in, const int* in_sizes, int n_in,
                              void* d_out, int out_size, void* d_ws, size_t ws_size,
                              hipStream_t stream) {
    const float* x   = (const float*)d_in[0];
    const int*   ei  = (const int*)d_in[1];
    const float* W1  = (const float*)d_in[2];
    const float* as1 = (const float*)d_in[3];
    const float* ad1 = (const float*)d_in[4];
    const float* b1  = (const float*)d_in[5];
    const float* W2  = (const float*)d_in[6];
    const float* as2 = (const float*)d_in[7];
    const float* ad2 = (const float*)d_in[8];
    const float* b2  = (const float*)d_in[9];
    float* out = (float*)d_out;
    int E = in_sizes[1] / 2;
    int TOT = E + N_NODES;

    int*   iws = (int*)d_ws;
    float* fws = (float*)d_ws;
    // ints (no memset needed: every word written before read)
    int* hist = iws;                       // NBH*NDIG = 262,144
    int* bcnt = iws + 262144;              // 1024
    int* boff = iws + 263168;              // 1024
    int* off  = iws + 264192;              // N
    int* deg  = iws + 364192;              // N
    int* pk   = iws + 464192;              // TOT
    int* ssrc = pk + TOT;                  // TOT
    size_t int_end = 464192 + 2 * (size_t)TOT;

    // part overlays the int scratch (ints written only after gemm1b consumed
    // part; kernels stream-serialize). Outputs of gemm1b (h1p..a2d) must NOT
    // overlap part -> with CH=4 (part=10M floats) move fbase above part.
    size_t part4_end = 4 * C1 * (size_t)N_NODES;           // 10,000,000
    size_t fbase4 = (part4_end > int_end ? part4_end : int_end);
    size_t need4 = (fbase4 + 4200000) * 4;
    bool use4 = ws_size >= need4;
    size_t fbase = use4 ? fbase4 : int_end;

    float* part = fws;
    float*  h1p  = fws + fbase;            // N*32  [asrc(5)|h1(25)|pad(2)]
    float*  adst = fws + fbase + 3200000;  // N*5
    float4* n2   = (float4*)(fws + fbase + 3700000); // N float4
    float*  a2d  = fws + fbase + 4100000;  // N

    dim3 blk(256);
    int NB1 = (N_NODES + 255) / 256;  // 391
    int nb64 = (N_NODES + 63) / 64;   // 1563
    if (use4) {
        k_gemm1<4><<<dim3(nb64 * 4), dim3(64), 0, stream>>>(x, W1, part);
        k_gemm1b<4><<<dim3(NB1), blk, 0, stream>>>(part, as1, ad1, h1p, adst);
    } else {
        k_gemm1<2><<<dim3(nb64 * 2), dim3(64), 0, stream>>>(x, W1, part);
        k_gemm1b<2><<<dim3(NB1), blk, 0, stream>>>(part, as1, ad1, h1p, adst);
    }
    k_hist1<<<dim3(NBH), dim3(HTH), 0, stream>>>(ei, E, TOT, hist);
    k_colscan<<<dim3(NDIG), dim3(NBH), 0, stream>>>(hist, bcnt);
    k_boff<<<dim3(1), dim3(NDIG), 0, stream>>>(bcnt, boff);
    k_write<<<dim3(NBH), dim3(HTH), 0, stream>>>(ei, E, TOT, hist, boff, pk);
    k_bgroup<<<dim3(NBUCK), dim3(512), 0, stream>>>(boff, bcnt, pk, off, deg, ssrc);
    k_layer1<<<dim3((N_NODES + NPB - 1) / NPB), dim3(NPB * HEADS), 0, stream>>>(
        off, deg, ssrc, h1p, adst, b1, W2, as2, ad2, n2, a2d);
    k_layer2<<<dim3(NB1), blk, 0, stream>>>(off, deg, ssrc, n2, a2d, b2, out);
}

// Round 11
// 344.327 us; speedup vs baseline: 1.0781x; 1.0781x over previous
//
#include <hip/hip_runtime.h>
#include <math.h>

#define N_NODES 100000
#define IN_DIM  512
#define HID     5
#define HEADS   5
#define C1      25   // HEADS*HID
#define NC      3
#define NEG     0.2f
#define NPB     64   // nodes per block in k_layer1
#define BSH     7    // 128 dsts per bucket
#define NBUCK   ((N_NODES + 127) >> BSH)   // 782
#define NDIG    1024 // padded bucket count (radix digits)
#define NBH     256  // hist/write blocks
#define HTH     1024 // hist/write threads per block

typedef float f32x4 __attribute__((ext_vector_type(4)));

__device__ __forceinline__ float lrelu(float v) { return v >= 0.f ? v : NEG * v; }

// ---- K1a: partial h1 = x @ W1, split-K x2, 1-wave blocks.
// Explicit fmaf chains (4 VALU per 4 MACs; no mul+add splits without
// fast-math) + explicit cur/nxt 2-line register pipeline so ~2 cache lines
// per wave stay in flight (VGPR ~96 -> 16 waves/CU cap, above measured
// demand of ~12). nt loads bypass L1 (2048B pow2 row stride -> one-set
// aliasing; zero reuse). W1 wave-uniform -> s_load.
template<int CH>
__global__ void __launch_bounds__(64)
k_gemm1(const float* __restrict__ x, const float* __restrict__ W1,
        float* __restrict__ part) {
    constexpr int KC = IN_DIM / CH;       // floats per chunk (256)
    constexpr int NB = KC / 32;           // 2-line batches (8)
    int b = blockIdx.x;
    int c = b & (CH - 1);
    int n = (b / CH) * 64 + threadIdx.x;
    if (n >= N_NODES) return;
    const f32x4* xr = (const f32x4*)(x + (size_t)n * IN_DIM) + c * (KC / 4);
    const float* Wb = W1 + (size_t)c * KC * C1;
    float acc[C1];
#pragma unroll
    for (int j = 0; j < C1; ++j) acc[j] = 0.f;
    f32x4 cur[8], nxt[8];
#pragma unroll
    for (int q = 0; q < 8; ++q) cur[q] = __builtin_nontemporal_load(xr + q);
    for (int L = 0; L < NB; ++L) {
        if (L < NB - 1) {
#pragma unroll
            for (int q = 0; q < 8; ++q)
                nxt[q] = __builtin_nontemporal_load(xr + (L + 1) * 8 + q);
        }
#pragma unroll
        for (int q = 0; q < 8; ++q) {
            const float* wr = Wb + (size_t)(L * 8 + q) * 4 * C1;  // wave-uniform -> s_load
            f32x4 xv = cur[q];
#pragma unroll
            for (int j = 0; j < C1; ++j)
                acc[j] = __builtin_fmaf(xv.w, wr[3 * C1 + j],
                         __builtin_fmaf(xv.z, wr[2 * C1 + j],
                         __builtin_fmaf(xv.y, wr[C1 + j],
                         __builtin_fmaf(xv.x, wr[j], acc[j]))));
        }
#pragma unroll
        for (int q = 0; q < 8; ++q) cur[q] = nxt[q];
    }
#pragma unroll
    for (int j = 0; j < C1; ++j)
        part[(size_t)(c * C1 + j) * N_NODES + n] = acc[j];   // coalesced store
}

// ---- K1b: reduce partials + epilogue (attention scalars, packed h1p row) ----
template<int CH>
__global__ void __launch_bounds__(256)
k_gemm1b(const float* __restrict__ part, const float* __restrict__ as1,
         const float* __restrict__ ad1, float* __restrict__ h1p,
         float* __restrict__ adst) {
    int n = blockIdx.x * blockDim.x + threadIdx.x;
    if (n >= N_NODES) return;
    float acc[C1];
#pragma unroll
    for (int j = 0; j < C1; ++j) acc[j] = 0.f;
#pragma unroll
    for (int c = 0; c < CH; ++c)
#pragma unroll
        for (int j = 0; j < C1; ++j)
            acc[j] += __builtin_nontemporal_load(part + (size_t)(c * C1 + j) * N_NODES + n);
    float rowbuf[32];
#pragma unroll
    for (int j = 0; j < C1; ++j) rowbuf[5 + j] = acc[j];
    rowbuf[30] = 0.f; rowbuf[31] = 0.f;
#pragma unroll
    for (int h = 0; h < HEADS; ++h) {
        float s = 0.f, d = 0.f;
#pragma unroll
        for (int c = 0; c < HID; ++c) {
            s += acc[h * HID + c] * as1[h * HID + c];
            d += acc[h * HID + c] * ad1[h * HID + c];
        }
        rowbuf[h] = s;
        adst[n * HEADS + h] = d;
    }
    float4* h4 = (float4*)(h1p + (size_t)n * 32);
#pragma unroll
    for (int q = 0; q < 8; ++q)
        h4[q] = make_float4(rowbuf[4 * q], rowbuf[4 * q + 1], rowbuf[4 * q + 2], rowbuf[4 * q + 3]);
}

// ---- radix pass 1: per-block LDS histogram over 1024 coarse buckets ----
__global__ void __launch_bounds__(HTH)
k_hist1(const int* __restrict__ ei, int E, int TOT, int* __restrict__ hist) {
    __shared__ int lh[NDIG];
    int b = blockIdx.x, tid = threadIdx.x;
    for (int i = tid; i < NDIG; i += HTH) lh[i] = 0;
    __syncthreads();
    int chunk = (TOT + NBH - 1) / NBH;
    int e0 = b * chunk, e1 = min(e0 + chunk, TOT);
    for (int e = e0 + tid; e < e1; e += HTH) {
        int d = (e < E) ? ei[E + e] : e - E;
        atomicAdd(&lh[d >> BSH], 1);
    }
    __syncthreads();
    for (int i = tid; i < NDIG; i += HTH) hist[b * NDIG + i] = lh[i];
}

// ---- radix: per-digit scan over blocks (hist[b][d] -> exclusive prefix; bcnt[d]=total) ----
__global__ void __launch_bounds__(NBH)
k_colscan(int* __restrict__ hist, int* __restrict__ bcnt) {
    __shared__ int sh[NBH];
    int d = blockIdx.x, t = threadIdx.x;
    int v = hist[t * NDIG + d];
    sh[t] = v;
    __syncthreads();
    for (int ofs = 1; ofs < NBH; ofs <<= 1) {
        int u = (t >= ofs) ? sh[t - ofs] : 0;
        __syncthreads();
        sh[t] += u;
        __syncthreads();
    }
    hist[t * NDIG + d] = sh[t] - v;   // exclusive over blocks
    if (t == NBH - 1) bcnt[d] = sh[t];
}

// ---- radix: exclusive scan of 1024 bucket counts ----
__global__ void __launch_bounds__(NDIG)
k_boff(const int* __restrict__ bcnt, int* __restrict__ boff) {
    __shared__ int sh[NDIG];
    int t = threadIdx.x;
    int v = bcnt[t];
    sh[t] = v;
    __syncthreads();
    for (int ofs = 1; ofs < NDIG; ofs <<= 1) {
        int u = (t >= ofs) ? sh[t - ofs] : 0;
        __syncthreads();
        sh[t] += u;
        __syncthreads();
    }
    boff[t] = sh[t] - v;
}

// ---- radix pass 2: write packed edges to bucket regions (LDS cursors, no global atomics) ----
__global__ void __launch_bounds__(HTH)
k_write(const int* __restrict__ ei, int E, int TOT, const int* __restrict__ hist,
        const int* __restrict__ boff, int* __restrict__ pk) {
    __shared__ int lbase[NDIG];
    __shared__ int lcur[NDIG];
    int b = blockIdx.x, tid = threadIdx.x;
    for (int i = tid; i < NDIG; i += HTH) {
        lbase[i] = boff[i] + hist[b * NDIG + i];
        lcur[i] = 0;
    }
    __syncthreads();
    int chunk = (TOT + NBH - 1) / NBH;
    int e0 = b * chunk, e1 = min(e0 + chunk, TOT);
    for (int e = e0 + tid; e < e1; e += HTH) {
        int s, d;
        if (e < E) { s = ei[e]; d = ei[E + e]; } else { s = d = e - E; }
        int dg = d >> BSH;
        int r = atomicAdd(&lcur[dg], 1);
        pk[lbase[dg] + r] = s | ((d & 127) << 17);
    }
}

// ---- per-bucket regroup by dst; emits off/deg and final ssrc (no global atomics) ----
__global__ void __launch_bounds__(512)
k_bgroup(const int* __restrict__ boff, const int* __restrict__ bcnt,
         const int* __restrict__ pk, int* __restrict__ off, int* __restrict__ deg,
         int* __restrict__ ssrc) {
    __shared__ int cnt[128], pref[128], lcur[128];
    int b = blockIdx.x, tid = threadIdx.x;
    int n0 = b << BSH;
    if (tid < 128) cnt[tid] = 0;
    __syncthreads();
    int r0 = boff[b], r1 = r0 + bcnt[b];
    for (int i = r0 + tid; i < r1; i += 512)
        atomicAdd(&cnt[(pk[i] >> 17) & 127], 1);
    __syncthreads();
    if (tid < 128) pref[tid] = cnt[tid];
    __syncthreads();
    for (int ofs = 1; ofs < 128; ofs <<= 1) {
        int u = 0;
        if (tid < 128 && tid >= ofs) u = pref[tid - ofs];
        __syncthreads();
        if (tid < 128) pref[tid] += u;
        __syncthreads();
    }
    if (tid < 128) {
        int n = n0 + tid;
        if (n < N_NODES) {
            off[n] = r0 + pref[tid] - cnt[tid];
            deg[n] = cnt[tid];
        }
        lcur[tid] = 0;
    }
    __syncthreads();
    for (int i = r0 + tid; i < r1; i += 512) {
        int v = pk[i];
        int dl = (v >> 17) & 127;
        int r = atomicAdd(&lcur[dl], 1);
        ssrc[r0 + pref[dl] - cnt[dl] + r] = v & 0x1FFFF;
    }
}

// ---- Layer 1: per-(dst,head) online softmax + aggregate; fused bias+ELU+W2+attn2 ----
__global__ void __launch_bounds__(NPB * HEADS)
k_layer1(const int* __restrict__ off, const int* __restrict__ deg, const int* __restrict__ ssrc,
         const float* __restrict__ h1p, const float* __restrict__ adst,
         const float* __restrict__ b1, const float* __restrict__ W2,
         const float* __restrict__ as2, const float* __restrict__ ad2,
         float4* __restrict__ n2, float* __restrict__ a2d) {
    __shared__ float sh[NPB * C1];
    int tid = threadIdx.x;            // 0..319
    int ln = tid / HEADS, h = tid % HEADS;
    int n = blockIdx.x * NPB + ln;
    if (n < N_NODES) {
        int st = off[n], cnt = deg[n];
        float adn = adst[n * HEADS + h];
        float m = -1e30f, den = 0.f;
        float num[HID] = {0.f, 0.f, 0.f, 0.f, 0.f};
        for (int i = 0; i < cnt; ++i) {
            int s = ssrc[st + i];
            const float* row = h1p + (size_t)s * 32;
            float v = lrelu(row[h] + adn);
            if (v > m) {
                float sc = __expf(m - v);
                den *= sc;
#pragma unroll
                for (int c = 0; c < HID; ++c) num[c] *= sc;
                m = v;
            }
            float p = __expf(v - m);
            den += p;
            const float* hr = row + 5 + h * HID;
#pragma unroll
            for (int c = 0; c < HID; ++c) num[c] += p * hr[c];
        }
        float inv = 1.f / den;
#pragma unroll
        for (int c = 0; c < HID; ++c) {
            float v = num[c] * inv + b1[h * HID + c];
            sh[ln * C1 + h * HID + c] = v > 0.f ? v : expm1f(v);
        }
    }
    __syncthreads();
    if (tid < NPB) {
        int nn = blockIdx.x * NPB + tid;
        if (nn < N_NODES) {
            float gg[NC] = {0.f, 0.f, 0.f};
#pragma unroll
            for (int j = 0; j < C1; ++j) {
                float hv = sh[tid * C1 + j];
#pragma unroll
                for (int c = 0; c < NC; ++c) gg[c] += hv * W2[j * NC + c];
            }
            float ssv = 0.f, ddv = 0.f;
#pragma unroll
            for (int c = 0; c < NC; ++c) { ssv += gg[c] * as2[c]; ddv += gg[c] * ad2[c]; }
            n2[nn] = make_float4(ssv, gg[0], gg[1], gg[2]);  // [a2s | g0 g1 g2]
            a2d[nn] = ddv;
        }
    }
}

// ---- Layer 2: per-dst online softmax + aggregate + log_sigmoid ----
__global__ void k_layer2(const int* __restrict__ off, const int* __restrict__ deg,
                         const int* __restrict__ ssrc, const float4* __restrict__ n2,
                         const float* __restrict__ a2d, const float* __restrict__ b2,
                         float* __restrict__ out) {
    int n = blockIdx.x * blockDim.x + threadIdx.x;
    if (n >= N_NODES) return;
    int st = off[n], cnt = deg[n];
    float adn = a2d[n];
    float m = -1e30f, den = 0.f, num0 = 0.f, num1 = 0.f, num2 = 0.f;
    for (int i = 0; i < cnt; ++i) {
        int s = ssrc[st + i];
        float4 gv = n2[s];
        float v = lrelu(gv.x + adn);
        if (v > m) {
            float sc = __expf(m - v);
            den *= sc; num0 *= sc; num1 *= sc; num2 *= sc;
            m = v;
        }
        float p = __expf(v - m);
        den += p;
        num0 += p * gv.y; num1 += p * gv.z; num2 += p * gv.w;
    }
    float inv = 1.f / den;
    float vv[NC] = {num0 * inv + b2[0], num1 * inv + b2[1], num2 * inv + b2[2]};
#pragma unroll
    for (int c = 0; c < NC; ++c) {
        float v = vv[c];
        out[n * NC + c] = (v >= 0.f) ? -log1pf(__expf(-v)) : v - log1pf(__expf(v));
    }
}

extern "C" void kernel_launch(void* const* d_in, const int* in_sizes, int n_in,
                              void* d_out, int out_size, void* d_ws, size_t ws_size,
                              hipStream_t stream) {
    const float* x   = (const float*)d_in[0];
    const int*   ei  = (const int*)d_in[1];
    const float* W1  = (const float*)d_in[2];
    const float* as1 = (const float*)d_in[3];
    const float* ad1 = (const float*)d_in[4];
    const float* b1  = (const float*)d_in[5];
    const float* W2  = (const float*)d_in[6];
    const float* as2 = (const float*)d_in[7];
    const float* ad2 = (const float*)d_in[8];
    const float* b2  = (const float*)d_in[9];
    float* out = (float*)d_out;
    int E = in_sizes[1] / 2;
    int TOT = E + N_NODES;

    int*   iws = (int*)d_ws;
    float* fws = (float*)d_ws;
    // ints (no memset needed: every word written before read)
    int* hist = iws;                       // NBH*NDIG = 262,144
    int* bcnt = iws + 262144;              // 1024
    int* boff = iws + 263168;              // 1024
    int* off  = iws + 264192;              // N
    int* deg  = iws + 364192;              // N
    int* pk   = iws + 464192;              // TOT
    int* ssrc = pk + TOT;                  // TOT
    size_t int_end = 464192 + 2 * (size_t)TOT;

    // part (CH=2 -> 5M floats) overlays the int scratch: fully consumed by
    // k_gemm1b before k_hist1..k_bgroup write hist/off/deg/pk (stream order).
    float* part = fws;
    size_t fbase = int_end;
    float*  h1p  = fws + fbase;            // N*32  [asrc(5)|h1(25)|pad(2)]
    float*  adst = fws + fbase + 3200000;  // N*5
    float4* n2   = (float4*)(fws + fbase + 3700000); // N float4
    float*  a2d  = fws + fbase + 4100000;  // N

    dim3 blk(256);
    int NB1 = (N_NODES + 255) / 256;  // 391
    int nb64 = (N_NODES + 63) / 64;   // 1563
    k_gemm1<2><<<dim3(nb64 * 2), dim3(64), 0, stream>>>(x, W1, part);
    k_gemm1b<2><<<dim3(NB1), blk, 0, stream>>>(part, as1, ad1, h1p, adst);
    k_hist1<<<dim3(NBH), dim3(HTH), 0, stream>>>(ei, E, TOT, hist);
    k_colscan<<<dim3(NDIG), dim3(NBH), 0, stream>>>(hist, bcnt);
    k_boff<<<dim3(1), dim3(NDIG), 0, stream>>>(bcnt, boff);
    k_write<<<dim3(NBH), dim3(HTH), 0, stream>>>(ei, E, TOT, hist, boff, pk);
    k_bgroup<<<dim3(NBUCK), dim3(512), 0, stream>>>(boff, bcnt, pk, off, deg, ssrc);
    k_layer1<<<dim3((N_NODES + NPB - 1) / NPB), dim3(NPB * HEADS), 0, stream>>>(
        off, deg, ssrc, h1p, adst, b1, W2, as2, ad2, n2, a2d);
    k_layer2<<<dim3(NB1), blk, 0, stream>>>(off, deg, ssrc, n2, a2d, b2, out);
}